// Round 11
// baseline (398.594 us; speedup 1.0000x reference)
//
#include <hip/hip_runtime.h>
#include <stdint.h>
#include <stddef.h>

typedef __bf16 bf16;
typedef __bf16 bf16x8 __attribute__((ext_vector_type(8)));
typedef __bf16 bf16x4 __attribute__((ext_vector_type(4)));
typedef short short4v __attribute__((ext_vector_type(4)));
typedef float f32x4 __attribute__((ext_vector_type(4)));

#define GAS __attribute__((address_space(1)))
#define LAS __attribute__((address_space(3)))

__device__ __forceinline__ void async_load16(const void* g, void* l) {
  __builtin_amdgcn_global_load_lds((const GAS void*)g, (LAS void*)l, 16, 0, 0);
}

// 16x16x16 bf16 MFMA. C-layout of a 16x16 MFMA == B-layout of this shape,
// so P^T feeds PV straight from registers. Host pass gets a stub.
__device__ __forceinline__ f32x4 mfma16(bf16x4 a, bf16x4 b, f32x4 c) {
#if defined(__HIP_DEVICE_COMPILE__)
#if __has_builtin(__builtin_amdgcn_mfma_f32_16x16x16bf16_1k)
  return __builtin_amdgcn_mfma_f32_16x16x16bf16_1k(
      __builtin_bit_cast(short4v, a), __builtin_bit_cast(short4v, b), c, 0, 0, 0);
#else
  f32x4 d;
  asm volatile("v_mfma_f32_16x16x16_bf16 %0, %1, %2, %3"
               : "=v"(d)
               : "v"(a), "v"(b), "v"(c));
  return d;
#endif
#else
  (void)a; (void)b;
  return c;
#endif
}

// ---------------------------------------------------------------------------
// Kernel 1: fp32 -> bf16 casts. Wq pre-scaled by 0.125*log2(e) so QK^T lands
// in the exp2 domain (scores Cauchy-Schwarz bounded -> no max subtraction).
// ---------------------------------------------------------------------------
__global__ __launch_bounds__(256) void cast_all(
    const float* __restrict__ x, const float* __restrict__ Wq,
    const float* __restrict__ Wk, const float* __restrict__ Wv,
    const float* __restrict__ Wo, bf16* __restrict__ Xh,
    bf16* __restrict__ Wqkv, bf16* __restrict__ Woh) {
  int idx = blockIdx.x * 256 + threadIdx.x;
  if (idx < 4194304) {
    Xh[idx] = (bf16)x[idx];
  } else if (idx < 7340032) {
    int j = idx - 4194304;
    if (j < 1048576) {
      Wqkv[j] = (bf16)(Wq[j] * 0.18033688011112042f);
    } else {
      const float* W = (j < 2097152) ? Wk : Wv;
      Wqkv[j] = (bf16)W[j & 1048575];
    }
  } else {
    int j = idx - 7340032;
    Woh[j] = (bf16)Wo[j];
  }
}

// ---------------------------------------------------------------------------
// Kernel 2: QKV projection with fused V-transpose epilogue.
// Cols <2048 (Q|K) -> QKV2 pitch 2048; cols >=2048 (V) -> Vt[bh][64][2048].
// ---------------------------------------------------------------------------
__global__ __launch_bounds__(256) void gemm_qkv(
    const bf16* __restrict__ A, const bf16* __restrict__ B,
    bf16* __restrict__ QKV2, bf16* __restrict__ Vt, int K) {
  __shared__ __align__(16) bf16 As[128 * 32];
  __shared__ __align__(16) bf16 Bs[128 * 32];
  const int tid = threadIdx.x;
  const int wave = tid >> 6, lane = tid & 63;
  const int bm = blockIdx.y * 128, bn = blockIdx.x * 128;
  const int wm = (wave >> 1) * 64, wn = (wave & 1) * 64;
  const int lrow = lane >> 2, lk = (lane & 3) * 8;
  const int fr = lane & 15, fk = (lane >> 4) * 8;

  f32x4 acc[4][4] = {};

  for (int kt = 0; kt < K; kt += 32) {
    __syncthreads();
#pragma unroll
    for (int c = 0; c < 2; ++c) {
      const int chunk = wave * 2 + c;
      const bf16* ga = A + (size_t)(bm + chunk * 16 + lrow) * K + kt + lk;
      async_load16(ga, (void*)(As + chunk * 512));
      const bf16* gb = B + (size_t)(bn + chunk * 16 + lrow) * K + kt + lk;
      async_load16(gb, (void*)(Bs + chunk * 512));
    }
    __syncthreads();

    bf16x8 af[4], bfr[4];
#pragma unroll
    for (int i = 0; i < 4; ++i)
      af[i] = *(const bf16x8*)&As[(wm + i * 16 + fr) * 32 + fk];
#pragma unroll
    for (int j = 0; j < 4; ++j)
      bfr[j] = *(const bf16x8*)&Bs[(wn + j * 16 + fr) * 32 + fk];
#pragma unroll
    for (int i = 0; i < 4; ++i)
#pragma unroll
      for (int j = 0; j < 4; ++j)
        acc[i][j] =
            __builtin_amdgcn_mfma_f32_16x16x32_bf16(af[i], bfr[j], acc[i][j], 0, 0, 0);
  }

  const int r0 = (lane >> 4) * 4, cc = lane & 15;
#pragma unroll
  for (int i = 0; i < 4; ++i) {
    const int row0 = bm + wm + i * 16 + r0;
#pragma unroll
    for (int j = 0; j < 4; ++j) {
      const int col = bn + wn + j * 16 + cc;
      if (col < 2048) {
#pragma unroll
        for (int r = 0; r < 4; ++r)
          QKV2[(size_t)(row0 + r) * 2048 + col] = (bf16)acc[i][j][r];
      } else {
        const int v = col - 2048, h = v >> 6, d = v & 63;
        const int b = row0 >> 11, s = row0 & 2047;
        bf16x4 o;
#pragma unroll
        for (int r = 0; r < 4; ++r) o[r] = (bf16)acc[i][j][r];
        *(bf16x4*)&Vt[(((size_t)b * 16 + h) * 64 + d) * 2048 + s] = o;
      }
    }
  }
}

// ---------------------------------------------------------------------------
// Kernel 2b (out-proj): C(MxN) = A(MxK) @ B(NxK)^T, fp32 out.
// ---------------------------------------------------------------------------
template <typename OutT, int BM, int BN>
__global__ __launch_bounds__(256) void gemm_bt(
    const bf16* __restrict__ A, const bf16* __restrict__ B,
    OutT* __restrict__ C, int M, int N, int K) {
  constexpr int ACH = BM / 16, NCH = (BM + BN) / 16, PW = NCH / 4;
  constexpr int FM = BM / 32, FN = BN / 32;
  __shared__ __align__(16) bf16 As[BM * 32];
  __shared__ __align__(16) bf16 Bs[BN * 32];
  const int tid = threadIdx.x;
  const int wave = tid >> 6, lane = tid & 63;
  const int bm = blockIdx.y * BM, bn = blockIdx.x * BN;
  const int wm = (wave >> 1) * (BM / 2), wn = (wave & 1) * (BN / 2);
  const int lrow = lane >> 2, lk = (lane & 3) * 8;
  const int fr = lane & 15, fk = (lane >> 4) * 8;

  f32x4 acc[FM][FN] = {};

  for (int kt = 0; kt < K; kt += 32) {
    __syncthreads();
#pragma unroll
    for (int c = 0; c < PW; ++c) {
      const int chunk = wave * PW + c;
      if (chunk < ACH) {
        const bf16* ga = A + (size_t)(bm + chunk * 16 + lrow) * K + kt + lk;
        async_load16(ga, (void*)(As + chunk * 512));
      } else {
        const int bc = chunk - ACH;
        const bf16* gb = B + (size_t)(bn + bc * 16 + lrow) * K + kt + lk;
        async_load16(gb, (void*)(Bs + bc * 512));
      }
    }
    __syncthreads();

    bf16x8 af[FM], bfr[FN];
#pragma unroll
    for (int i = 0; i < FM; ++i)
      af[i] = *(const bf16x8*)&As[(wm + i * 16 + fr) * 32 + fk];
#pragma unroll
    for (int j = 0; j < FN; ++j)
      bfr[j] = *(const bf16x8*)&Bs[(wn + j * 16 + fr) * 32 + fk];
#pragma unroll
    for (int i = 0; i < FM; ++i)
#pragma unroll
      for (int j = 0; j < FN; ++j)
        acc[i][j] =
            __builtin_amdgcn_mfma_f32_16x16x32_bf16(af[i], bfr[j], acc[i][j], 0, 0, 0);
  }

  const int r0 = (lane >> 4) * 4, cc = lane & 15;
#pragma unroll
  for (int i = 0; i < FM; ++i)
#pragma unroll
    for (int j = 0; j < FN; ++j)
#pragma unroll
      for (int r = 0; r < 4; ++r)
        C[(size_t)(bm + wm + i * 16 + r0 + r) * N + (bn + wn + j * 16 + cc)] =
            (OutT)acc[i][j][r];
}

// ---------------------------------------------------------------------------
// Kernel 3: RoPE on Q|K (QKV2, pitch 2048) + scatter to [bh][s][64].
// ---------------------------------------------------------------------------
__global__ __launch_bounds__(256) void rope_qk(const bf16* __restrict__ QKV2,
                                               bf16* __restrict__ Qh,
                                               bf16* __restrict__ Kh) {
  int idx = blockIdx.x * 256 + threadIdx.x;
  int row = idx >> 10, cp = idx & 1023;
  int col = cp << 1;  // 0..2046
  size_t base = (size_t)row * 2048 + col;
  float xe = (float)QKV2[base], xo = (float)QKV2[base + 1];
  int s = row & 2047, b = row >> 11;
  int i = cp & 31;
  float freq = __expf((float)i * -0.2878231366242557f);  // ln(10000)/32
  float sn, cs;
  __sincosf((float)s * freq, &sn, &cs);
  float re = xe * cs - xo * sn;
  float ro = xe * sn + xo * cs;
  int hcol = col & 1023;
  int h = hcol >> 6, d = hcol & 63;
  bf16* dst = (col < 1024 ? Qh : Kh) + ((size_t)(b * 16 + h) * 2048 + s) * 64 + d;
  dst[0] = (bf16)re;
  dst[1] = (bf16)ro;
}

// ---------------------------------------------------------------------------
// Kernel 4: causal attention, 4-way intra-block split-K.
// ROUND-11 FIX: round 9/10's persistent pk[4][2] prefetch (+32 VGPRs) blew
// the 128-VGPR allocation and spilled (WRITE 27-406 MB). K fragments are now
// loaded at point of use (transient, like round 8 which fit 128 VGPRs with
// WRITE=8MB). oacc lives on the unified AGPR side. (256,4) pins 128 VGPRs ->
// 4 waves/SIMD, 16 waves/CU, chains <=8 tiles (half of round 8's 16).
// k-loop barrier-free (private Vs per wave, pv prefetch 1 tile ahead);
// end combine tree on scratch aliased over dead Vs.
// ---------------------------------------------------------------------------
__global__ __launch_bounds__(256, 4) void attn(const bf16* __restrict__ Qh,
                                               const bf16* __restrict__ Kh,
                                               const bf16* __restrict__ Vt,
                                               bf16* __restrict__ Oh) {
  __shared__ __align__(16) char smem[4 * 64 * 72 * 2];  // Vs[4] / scratch x2
  const int qt = 31 - (int)blockIdx.x;  // LPT: long blocks dispatch first
  const int bh = blockIdx.y;
  const int tid = threadIdx.x, w = tid >> 6, lane = tid & 63;
  const int nlo = lane & 15, g = lane >> 4;
  const int q0 = qt * 64;
  const bf16* __restrict__ Qp = Qh + (size_t)bh * 131072;
  const bf16* __restrict__ Kp = Kh + (size_t)bh * 131072;
  const bf16* __restrict__ Vp = Vt + (size_t)bh * 131072;
  const int n = qt + 1;  // k-tiles for this Q-tile
  const int t0 = (n * w) >> 2, t1 = (n * (w + 1)) >> 2;  // this wave's chunk
  const int cnt = t1 - t0;

  // Q fragments, all 4 q-subtiles (B-operand: n=q=nlo, k=d=g*8+j)
  bf16x8 aq[4][2];
#pragma unroll
  for (int qb = 0; qb < 4; ++qb)
#pragma unroll
    for (int ks = 0; ks < 2; ++ks)
      aq[qb][ks] =
          *(const bf16x8*)&Qp[(size_t)(q0 + qb * 16 + nlo) * 64 + ks * 32 + g * 8];

  f32x4 oacc[4][4] = {};  // [qb][d-block], O^T C-layout (m=d, n=q)
  float lsum[4] = {0.f, 0.f, 0.f, 0.f};

  // V staging geometry: instr c covers rows c*8..c*8+7
  const int srow = lane >> 3, soff = (lane & 7) * 8;
  bf16* __restrict__ Vw = (bf16*)smem + w * 4608;  // 64*72

  bf16x8 pv[8];
  if (cnt > 0) {
#pragma unroll
    for (int c = 0; c < 8; ++c)
      pv[c] = *(const bf16x8*)&Vp[(size_t)(c * 8 + srow) * 2048 + t0 * 64 + soff];
  }

  for (int it = 0; it < cnt; ++it) {
    const int i = t0 + it, kbase = i * 64;
    // K fragments at point of use (transient; L2-hot; no persistent regs)
    bf16x8 pk[4][2];
#pragma unroll
    for (int ni = 0; ni < 4; ++ni)
#pragma unroll
      for (int ks = 0; ks < 2; ++ks)
        pk[ni][ks] = *(const bf16x8*)&Kp[(size_t)(kbase + ni * 16 + nlo) * 64 +
                                         ks * 32 + g * 8];
    // commit V tile (wave-private; waitcnt ordering only, no barrier)
#pragma unroll
    for (int c = 0; c < 8; ++c)
      *(bf16x8*)&Vw[(c * 8 + srow) * 72 + soff] = pv[c];
    // prefetch next V tile
    if (it + 1 < cnt) {
      const int kb2 = kbase + 64;
#pragma unroll
      for (int c = 0; c < 8; ++c)
        pv[c] = *(const bf16x8*)&Vp[(size_t)(c * 8 + srow) * 2048 + kb2 + soff];
    }

    // S^T = K.Q^T, p = exp2(S^T) in regs, l accumulated in-lane
    const bool dg = (i == n - 1);
    bf16x4 p[4][4];
#pragma unroll
    for (int qb = 0; qb < 4; ++qb) {
      f32x4 st[4] = {};
#pragma unroll
      for (int ks = 0; ks < 2; ++ks)
#pragma unroll
        for (int ni = 0; ni < 4; ++ni)
          st[ni] = __builtin_amdgcn_mfma_f32_16x16x32_bf16(pk[ni][ks], aq[qb][ks],
                                                           st[ni], 0, 0, 0);
      const int qg = q0 + qb * 16 + nlo;
#pragma unroll
      for (int ni = 0; ni < 4; ++ni) {
        const int kg0 = kbase + ni * 16 + g * 4;
#pragma unroll
        for (int r = 0; r < 4; ++r) {
          float e = __builtin_amdgcn_exp2f(st[ni][r]);
          e = (!dg || (kg0 + r <= qg)) ? e : 0.0f;
          lsum[qb] += e;
          p[qb][ni][r] = (bf16)e;
        }
      }
    }

    // O^T += V^T.P  (av read once, shared across all 4 q-subtiles)
#pragma unroll
    for (int ni = 0; ni < 4; ++ni)
#pragma unroll
      for (int mi = 0; mi < 4; ++mi) {
        bf16x4 av = *(const bf16x4*)&Vw[(mi * 16 + nlo) * 72 + ni * 16 + g * 4];
#pragma unroll
        for (int qb = 0; qb < 4; ++qb)
          oacc[qb][mi] = mfma16(av, p[qb][ni], oacc[qb][mi]);
      }
  }

  // finish l: reduce over the 4 g-groups (columns are per-nlo)
#pragma unroll
  for (int qb = 0; qb < 4; ++qb) {
    lsum[qb] += __shfl_xor(lsum[qb], 16, 64);
    lsum[qb] += __shfl_xor(lsum[qb], 32, 64);
  }

  // ---- combine tree (scratch aliases Vs; k-loop is done for all waves) ----
  float* sc0 = (float*)smem;           // 68*64 floats
  float* sc1 = (float*)smem + 4352;    // second buffer
  __syncthreads();  // all waves done with every Vs before aliasing
  if (w == 1 || w == 3) {
    float* sc = (w == 1) ? sc0 : sc1;
#pragma unroll
    for (int qb = 0; qb < 4; ++qb) {
#pragma unroll
      for (int mi = 0; mi < 4; ++mi)
#pragma unroll
        for (int r = 0; r < 4; ++r)
          sc[(qb * 16 + mi * 4 + r) * 64 + lane] = oacc[qb][mi][r];
      sc[(64 + qb) * 64 + lane] = lsum[qb];
    }
  }
  __syncthreads();
  if (w == 0) {
#pragma unroll
    for (int qb = 0; qb < 4; ++qb) {
#pragma unroll
      for (int mi = 0; mi < 4; ++mi)
#pragma unroll
        for (int r = 0; r < 4; ++r)
          oacc[qb][mi][r] += sc0[(qb * 16 + mi * 4 + r) * 64 + lane] +
                             sc1[(qb * 16 + mi * 4 + r) * 64 + lane];
      lsum[qb] += sc0[(64 + qb) * 64 + lane] + sc1[(64 + qb) * 64 + lane];
    }
  }
  __syncthreads();
  if (w == 2) {
#pragma unroll
    for (int qb = 0; qb < 4; ++qb) {
#pragma unroll
      for (int mi = 0; mi < 4; ++mi)
#pragma unroll
        for (int r = 0; r < 4; ++r)
          sc0[(qb * 16 + mi * 4 + r) * 64 + lane] = oacc[qb][mi][r];
      sc0[(64 + qb) * 64 + lane] = lsum[qb];
    }
  }
  __syncthreads();
  if (w == 0) {
    const int b = bh >> 4, hd = bh & 15;
#pragma unroll
    for (int qb = 0; qb < 4; ++qb) {
      const float l = lsum[qb] + sc0[(64 + qb) * 64 + lane];
      const float inv = 1.0f / l;
      const int q = q0 + qb * 16 + nlo;
#pragma unroll
      for (int mi = 0; mi < 4; ++mi) {
        bf16x4 o;
#pragma unroll
        for (int r = 0; r < 4; ++r)
          o[r] = (bf16)((oacc[qb][mi][r] +
                         sc0[(qb * 16 + mi * 4 + r) * 64 + lane]) * inv);
        *(bf16x4*)&Oh[((size_t)b * 2048 + q) * 1024 + hd * 64 + mi * 16 + g * 4] = o;
      }
    }
  }
}

// ---------------------------------------------------------------------------
extern "C" void kernel_launch(void* const* d_in, const int* in_sizes, int n_in,
                              void* d_out, int out_size, void* d_ws, size_t ws_size,
                              hipStream_t stream) {
  (void)in_sizes; (void)n_in; (void)out_size; (void)ws_size;
  const float* x = (const float*)d_in[0];
  const float* Wq = (const float*)d_in[1];
  const float* Wk = (const float*)d_in[2];
  const float* Wv = (const float*)d_in[3];
  const float* Wo = (const float*)d_in[4];
  float* out = (float*)d_out;
  char* ws = (char*)d_ws;

  bf16* Xh   = (bf16*)(ws);                 // 4096x1024          8 MB
  bf16* Wqkv = (bf16*)(ws + 8388608);       // 3072x1024          6 MB
  bf16* Woh  = (bf16*)(ws + 14680064);      // 1024x1024          2 MB
  bf16* QKV2 = (bf16*)(ws + 16777216);      // 4096x2048 (Q|K)   16 MB
  bf16* Qh   = (bf16*)(ws + 33554432);      // [32][2048][64]     8 MB
  bf16* Kh   = (bf16*)(ws + 41943040);      // [32][2048][64]     8 MB
  bf16* Vt   = (bf16*)(ws + 50331648);      // [32][64][2048]     8 MB
  bf16* Oh   = (bf16*)(ws + 58720256);      // 4096x1024          8 MB

  cast_all<<<32768, 256, 0, stream>>>(x, Wq, Wk, Wv, Wo, Xh, Wqkv, Woh);
  gemm_qkv<<<dim3(24, 32), 256, 0, stream>>>(Xh, Wqkv, QKV2, Vt, 1024);
  rope_qk<<<16384, 256, 0, stream>>>(QKV2, Qh, Kh);
  attn<<<dim3(32, 32), 256, 0, stream>>>(Qh, Kh, Vt, Oh);
  gemm_bt<float, 128, 64><<<dim3(16, 32), 256, 0, stream>>>(Oh, Woh, out, 4096, 1024, 1024);
}

// Round 12
// 196.385 us; speedup vs baseline: 2.0297x; 2.0297x over previous
//
#include <hip/hip_runtime.h>
#include <stdint.h>
#include <stddef.h>

typedef __bf16 bf16;
typedef __bf16 bf16x8 __attribute__((ext_vector_type(8)));
typedef __bf16 bf16x4 __attribute__((ext_vector_type(4)));
typedef short short4v __attribute__((ext_vector_type(4)));
typedef float f32x4 __attribute__((ext_vector_type(4)));

#define GAS __attribute__((address_space(1)))
#define LAS __attribute__((address_space(3)))

__device__ __forceinline__ void async_load16(const void* g, void* l) {
  __builtin_amdgcn_global_load_lds((const GAS void*)g, (LAS void*)l, 16, 0, 0);
}

// 16x16x16 bf16 MFMA. C-layout of a 16x16 MFMA == B-layout of this shape,
// so P^T feeds PV straight from registers. Host pass gets a stub.
__device__ __forceinline__ f32x4 mfma16(bf16x4 a, bf16x4 b, f32x4 c) {
#if defined(__HIP_DEVICE_COMPILE__)
#if __has_builtin(__builtin_amdgcn_mfma_f32_16x16x16bf16_1k)
  return __builtin_amdgcn_mfma_f32_16x16x16bf16_1k(
      __builtin_bit_cast(short4v, a), __builtin_bit_cast(short4v, b), c, 0, 0, 0);
#else
  f32x4 d;
  asm volatile("v_mfma_f32_16x16x16_bf16 %0, %1, %2, %3"
               : "=v"(d)
               : "v"(a), "v"(b), "v"(c));
  return d;
#endif
#else
  (void)a; (void)b;
  return c;
#endif
}

// ---------------------------------------------------------------------------
// Kernel 1: fp32 -> bf16 casts, x4 vectorized (float4 loads; all region
// boundaries are multiples of 4). Wq pre-scaled by 0.125*log2(e).
// ---------------------------------------------------------------------------
__global__ __launch_bounds__(256) void cast_all(
    const float* __restrict__ x, const float* __restrict__ Wq,
    const float* __restrict__ Wk, const float* __restrict__ Wv,
    const float* __restrict__ Wo, bf16* __restrict__ Xh,
    bf16* __restrict__ Wqkv, bf16* __restrict__ Woh) {
  int idx = (blockIdx.x * 256 + threadIdx.x) * 4;
  const float* src;
  bf16* dst;
  float scale = 1.0f;
  if (idx < 4194304) {
    src = x + idx; dst = Xh + idx;
  } else if (idx < 7340032) {
    int j = idx - 4194304;
    if (j < 1048576) {
      src = Wq + j; scale = 0.18033688011112042f;
    } else {
      src = ((j < 2097152) ? Wk : Wv) + (j & 1048575);
    }
    dst = Wqkv + j;
  } else {
    int j = idx - 7340032;
    src = Wo + j; dst = Woh + j;
  }
  float4 v = *(const float4*)src;
  bf16x4 o;
  o[0] = (bf16)(v.x * scale); o[1] = (bf16)(v.y * scale);
  o[2] = (bf16)(v.z * scale); o[3] = (bf16)(v.w * scale);
  *(bf16x4*)dst = o;
}

// ---------------------------------------------------------------------------
// Kernel 2: QKV projection with fused V-transpose epilogue.
// Cols <2048 (Q|K) -> QKV2 pitch 2048; cols >=2048 (V) -> Vt[bh][64][2048].
// ---------------------------------------------------------------------------
__global__ __launch_bounds__(256) void gemm_qkv(
    const bf16* __restrict__ A, const bf16* __restrict__ B,
    bf16* __restrict__ QKV2, bf16* __restrict__ Vt, int K) {
  __shared__ __align__(16) bf16 As[128 * 32];
  __shared__ __align__(16) bf16 Bs[128 * 32];
  const int tid = threadIdx.x;
  const int wave = tid >> 6, lane = tid & 63;
  const int bm = blockIdx.y * 128, bn = blockIdx.x * 128;
  const int wm = (wave >> 1) * 64, wn = (wave & 1) * 64;
  const int lrow = lane >> 2, lk = (lane & 3) * 8;
  const int fr = lane & 15, fk = (lane >> 4) * 8;

  f32x4 acc[4][4] = {};

  for (int kt = 0; kt < K; kt += 32) {
    __syncthreads();
#pragma unroll
    for (int c = 0; c < 2; ++c) {
      const int chunk = wave * 2 + c;
      const bf16* ga = A + (size_t)(bm + chunk * 16 + lrow) * K + kt + lk;
      async_load16(ga, (void*)(As + chunk * 512));
      const bf16* gb = B + (size_t)(bn + chunk * 16 + lrow) * K + kt + lk;
      async_load16(gb, (void*)(Bs + chunk * 512));
    }
    __syncthreads();

    bf16x8 af[4], bfr[4];
#pragma unroll
    for (int i = 0; i < 4; ++i)
      af[i] = *(const bf16x8*)&As[(wm + i * 16 + fr) * 32 + fk];
#pragma unroll
    for (int j = 0; j < 4; ++j)
      bfr[j] = *(const bf16x8*)&Bs[(wn + j * 16 + fr) * 32 + fk];
#pragma unroll
    for (int i = 0; i < 4; ++i)
#pragma unroll
      for (int j = 0; j < 4; ++j)
        acc[i][j] =
            __builtin_amdgcn_mfma_f32_16x16x32_bf16(af[i], bfr[j], acc[i][j], 0, 0, 0);
  }

  const int r0 = (lane >> 4) * 4, cc = lane & 15;
#pragma unroll
  for (int i = 0; i < 4; ++i) {
    const int row0 = bm + wm + i * 16 + r0;
#pragma unroll
    for (int j = 0; j < 4; ++j) {
      const int col = bn + wn + j * 16 + cc;
      if (col < 2048) {
#pragma unroll
        for (int r = 0; r < 4; ++r)
          QKV2[(size_t)(row0 + r) * 2048 + col] = (bf16)acc[i][j][r];
      } else {
        const int v = col - 2048, h = v >> 6, d = v & 63;
        const int b = row0 >> 11, s = row0 & 2047;
        bf16x4 o;
#pragma unroll
        for (int r = 0; r < 4; ++r) o[r] = (bf16)acc[i][j][r];
        *(bf16x4*)&Vt[(((size_t)b * 16 + h) * 64 + d) * 2048 + s] = o;
      }
    }
  }
}

// ---------------------------------------------------------------------------
// Kernel 2b (out-proj): C(MxN) = A(MxK) @ B(NxK)^T, fp32 out.
// ---------------------------------------------------------------------------
template <typename OutT, int BM, int BN>
__global__ __launch_bounds__(256) void gemm_bt(
    const bf16* __restrict__ A, const bf16* __restrict__ B,
    OutT* __restrict__ C, int M, int N, int K) {
  constexpr int ACH = BM / 16, NCH = (BM + BN) / 16, PW = NCH / 4;
  constexpr int FM = BM / 32, FN = BN / 32;
  __shared__ __align__(16) bf16 As[BM * 32];
  __shared__ __align__(16) bf16 Bs[BN * 32];
  const int tid = threadIdx.x;
  const int wave = tid >> 6, lane = tid & 63;
  const int bm = blockIdx.y * BM, bn = blockIdx.x * BN;
  const int wm = (wave >> 1) * (BM / 2), wn = (wave & 1) * (BN / 2);
  const int lrow = lane >> 2, lk = (lane & 3) * 8;
  const int fr = lane & 15, fk = (lane >> 4) * 8;

  f32x4 acc[FM][FN] = {};

  for (int kt = 0; kt < K; kt += 32) {
    __syncthreads();
#pragma unroll
    for (int c = 0; c < PW; ++c) {
      const int chunk = wave * PW + c;
      if (chunk < ACH) {
        const bf16* ga = A + (size_t)(bm + chunk * 16 + lrow) * K + kt + lk;
        async_load16(ga, (void*)(As + chunk * 512));
      } else {
        const int bc = chunk - ACH;
        const bf16* gb = B + (size_t)(bn + bc * 16 + lrow) * K + kt + lk;
        async_load16(gb, (void*)(Bs + bc * 512));
      }
    }
    __syncthreads();

    bf16x8 af[FM], bfr[FN];
#pragma unroll
    for (int i = 0; i < FM; ++i)
      af[i] = *(const bf16x8*)&As[(wm + i * 16 + fr) * 32 + fk];
#pragma unroll
    for (int j = 0; j < FN; ++j)
      bfr[j] = *(const bf16x8*)&Bs[(wn + j * 16 + fr) * 32 + fk];
#pragma unroll
    for (int i = 0; i < FM; ++i)
#pragma unroll
      for (int j = 0; j < FN; ++j)
        acc[i][j] =
            __builtin_amdgcn_mfma_f32_16x16x32_bf16(af[i], bfr[j], acc[i][j], 0, 0, 0);
  }

  const int r0 = (lane >> 4) * 4, cc = lane & 15;
#pragma unroll
  for (int i = 0; i < FM; ++i)
#pragma unroll
    for (int j = 0; j < FN; ++j)
#pragma unroll
      for (int r = 0; r < 4; ++r)
        C[(size_t)(bm + wm + i * 16 + r0 + r) * N + (bn + wn + j * 16 + cc)] =
            (OutT)acc[i][j][r];
}

// ---------------------------------------------------------------------------
// Kernel 3: RoPE on Q|K, x4 vectorized: one thread = 4 pairs (bf16x8 in/out;
// a group of 4 pairs never straddles a head or the Q/K boundary since 8|64).
// ---------------------------------------------------------------------------
__global__ __launch_bounds__(256) void rope_qk(const bf16* __restrict__ QKV2,
                                               bf16* __restrict__ Qh,
                                               bf16* __restrict__ Kh) {
  int idx = blockIdx.x * 256 + threadIdx.x;  // 4096 rows x 256 groups
  int row = idx >> 8, grp = idx & 255;
  int col = grp << 3;  // 0..2040, 8-aligned
  bf16x8 v = *(const bf16x8*)&QKV2[(size_t)row * 2048 + col];
  int s = row & 2047, b = row >> 11;
  bf16x8 o;
#pragma unroll
  for (int k = 0; k < 4; ++k) {
    int cp = (col >> 1) + k;   // global pair index
    int i = cp & 31;           // pair index within head
    float freq = __expf((float)i * -0.2878231366242557f);  // ln(10000)/32
    float sn, cs;
    __sincosf((float)s * freq, &sn, &cs);
    float xe = (float)v[2 * k], xo = (float)v[2 * k + 1];
    o[2 * k] = (bf16)(xe * cs - xo * sn);
    o[2 * k + 1] = (bf16)(xe * sn + xo * cs);
  }
  int hcol = col & 1023;
  int h = hcol >> 6, d = hcol & 63;
  bf16* dst = (col < 1024 ? Qh : Kh) + ((size_t)(b * 16 + h) * 2048 + s) * 64 + d;
  *(bf16x8*)dst = o;
}

// ---------------------------------------------------------------------------
// Kernel 4: causal attention — round-8 configuration verbatim (best measured:
// 60us, VGPR 128, zero spill). Block = 128 threads = 2 INDEPENDENT waves
// splitting one 64-row Q-tile's key range (unnormalized exp2 streaming is
// additive). Barrier-free k-loop: private padded Vs per wave, K frags at
// point of use from global (L2-hot), V register-prefetch 1 tile ahead, P in
// regs (C-layout == 16x16x16 B-layout), l in-lane + 2 end shuffles. One
// barrier total: wave1 dumps partial O/l to LDS, wave0 combines + stores.
// ---------------------------------------------------------------------------
__global__ __launch_bounds__(128, 2) void attn(const bf16* __restrict__ Qh,
                                               const bf16* __restrict__ Kh,
                                               const bf16* __restrict__ Vt,
                                               bf16* __restrict__ Oh) {
  __shared__ __align__(16) bf16 Vs[2][64 * 72];  // per-wave private
  __shared__ float scratch[68 * 64];             // combine area
  const int f = blockIdx.x;
  const int qt = 31 - (f >> 5);  // LPT: longest (qt=31) blocks dispatch first
  const int bh = f & 31;
  const int tid = threadIdx.x, w = tid >> 6, lane = tid & 63;
  const int nlo = lane & 15, g = lane >> 4;
  const int q0 = qt * 64;
  const bf16* __restrict__ Qp = Qh + (size_t)bh * 131072;
  const bf16* __restrict__ Kp = Kh + (size_t)bh * 131072;
  const bf16* __restrict__ Vp = Vt + (size_t)bh * 131072;
  const int n = qt + 1;          // total k-tiles for this Q-tile
  const int hf = (n + 1) >> 1;   // wave0: [0,hf), wave1: [hf,n)
  const int t0 = w ? hf : 0;
  const int cnt = w ? (n - hf) : hf;

  // Q fragments, all 4 q-subtiles (B-operand: n=q=nlo, k=d=g*8+j)
  bf16x8 aq[4][2];
#pragma unroll
  for (int qb = 0; qb < 4; ++qb)
#pragma unroll
    for (int ks = 0; ks < 2; ++ks)
      aq[qb][ks] =
          *(const bf16x8*)&Qp[(size_t)(q0 + qb * 16 + nlo) * 64 + ks * 32 + g * 8];

  f32x4 oacc[4][4] = {};  // [qb][d-block], O^T C-layout (m=d, n=q)
  float lsum[4] = {0.f, 0.f, 0.f, 0.f};

  // V staging geometry: instr c covers rows c*8..c*8+7
  const int srow = lane >> 3, soff = (lane & 7) * 8;
  bf16* __restrict__ Vw = Vs[w];

  bf16x8 pv[8];
  if (cnt > 0) {
#pragma unroll
    for (int c = 0; c < 8; ++c)
      pv[c] = *(const bf16x8*)&Vp[(size_t)(c * 8 + srow) * 2048 + t0 * 64 + soff];
  }

  for (int it = 0; it < cnt; ++it) {
    const int i = t0 + it, kbase = i * 64;
    // K fragments straight from global (L2-hot; transient registers)
    bf16x8 pk[4][2];
#pragma unroll
    for (int ni = 0; ni < 4; ++ni)
#pragma unroll
      for (int ks = 0; ks < 2; ++ks)
        pk[ni][ks] = *(const bf16x8*)&Kp[(size_t)(kbase + ni * 16 + nlo) * 64 +
                                         ks * 32 + g * 8];
    // commit V tile (wave-private; waitcnt ordering only, no barrier)
#pragma unroll
    for (int c = 0; c < 8; ++c)
      *(bf16x8*)&Vw[(c * 8 + srow) * 72 + soff] = pv[c];
    // prefetch next V tile
    if (it + 1 < cnt) {
      const int kb2 = kbase + 64;
#pragma unroll
      for (int c = 0; c < 8; ++c)
        pv[c] = *(const bf16x8*)&Vp[(size_t)(c * 8 + srow) * 2048 + kb2 + soff];
    }

    // S^T = K.Q^T, p = exp2(S^T) in regs, l accumulated in-lane
    const bool dg = (i == n - 1);
    bf16x4 p[4][4];
#pragma unroll
    for (int qb = 0; qb < 4; ++qb) {
      f32x4 st[4] = {};
#pragma unroll
      for (int ks = 0; ks < 2; ++ks)
#pragma unroll
        for (int ni = 0; ni < 4; ++ni)
          st[ni] = __builtin_amdgcn_mfma_f32_16x16x32_bf16(pk[ni][ks], aq[qb][ks],
                                                           st[ni], 0, 0, 0);
      const int qg = q0 + qb * 16 + nlo;
#pragma unroll
      for (int ni = 0; ni < 4; ++ni) {
        const int kg0 = kbase + ni * 16 + g * 4;
#pragma unroll
        for (int r = 0; r < 4; ++r) {
          float e = __builtin_amdgcn_exp2f(st[ni][r]);
          e = (!dg || (kg0 + r <= qg)) ? e : 0.0f;
          lsum[qb] += e;
          p[qb][ni][r] = (bf16)e;
        }
      }
    }

    // O^T += V^T.P  (av read once, shared across all 4 q-subtiles)
#pragma unroll
    for (int ni = 0; ni < 4; ++ni)
#pragma unroll
      for (int mi = 0; mi < 4; ++mi) {
        bf16x4 av = *(const bf16x4*)&Vw[(mi * 16 + nlo) * 72 + ni * 16 + g * 4];
#pragma unroll
        for (int qb = 0; qb < 4; ++qb)
          oacc[qb][mi] = mfma16(av, p[qb][ni], oacc[qb][mi]);
      }
  }

  // finish l: reduce over the 4 g-groups (columns are per-nlo)
#pragma unroll
  for (int qb = 0; qb < 4; ++qb) {
    lsum[qb] += __shfl_xor(lsum[qb], 16, 64);
    lsum[qb] += __shfl_xor(lsum[qb], 32, 64);
  }

  // combine: wave1 -> LDS (column-major f32 = conflict-free), wave0 adds
  if (w == 1) {
#pragma unroll
    for (int qb = 0; qb < 4; ++qb) {
#pragma unroll
      for (int mi = 0; mi < 4; ++mi)
#pragma unroll
        for (int r = 0; r < 4; ++r)
          scratch[(qb * 16 + mi * 4 + r) * 64 + lane] = oacc[qb][mi][r];
      scratch[(64 + qb) * 64 + lane] = lsum[qb];
    }
  }
  __syncthreads();
  if (w == 0) {
    const int b = bh >> 4, hd = bh & 15;
#pragma unroll
    for (int qb = 0; qb < 4; ++qb) {
      const float l = lsum[qb] + scratch[(64 + qb) * 64 + lane];
      const float inv = 1.0f / l;
      const int q = q0 + qb * 16 + nlo;
#pragma unroll
      for (int mi = 0; mi < 4; ++mi) {
        bf16x4 o;
#pragma unroll
        for (int r = 0; r < 4; ++r)
          o[r] = (bf16)((oacc[qb][mi][r] +
                         scratch[(qb * 16 + mi * 4 + r) * 64 + lane]) * inv);
        *(bf16x4*)&Oh[((size_t)b * 2048 + q) * 1024 + hd * 64 + mi * 16 + g * 4] = o;
      }
    }
  }
}

// ---------------------------------------------------------------------------
extern "C" void kernel_launch(void* const* d_in, const int* in_sizes, int n_in,
                              void* d_out, int out_size, void* d_ws, size_t ws_size,
                              hipStream_t stream) {
  (void)in_sizes; (void)n_in; (void)out_size; (void)ws_size;
  const float* x = (const float*)d_in[0];
  const float* Wq = (const float*)d_in[1];
  const float* Wk = (const float*)d_in[2];
  const float* Wv = (const float*)d_in[3];
  const float* Wo = (const float*)d_in[4];
  float* out = (float*)d_out;
  char* ws = (char*)d_ws;

  bf16* Xh   = (bf16*)(ws);                 // 4096x1024          8 MB
  bf16* Wqkv = (bf16*)(ws + 8388608);       // 3072x1024          6 MB
  bf16* Woh  = (bf16*)(ws + 14680064);      // 1024x1024          2 MB
  bf16* QKV2 = (bf16*)(ws + 16777216);      // 4096x2048 (Q|K)   16 MB
  bf16* Qh   = (bf16*)(ws + 33554432);      // [32][2048][64]     8 MB
  bf16* Kh   = (bf16*)(ws + 41943040);      // [32][2048][64]     8 MB
  bf16* Vt   = (bf16*)(ws + 50331648);      // [32][64][2048]     8 MB
  bf16* Oh   = (bf16*)(ws + 58720256);      // 4096x1024          8 MB

  cast_all<<<8192, 256, 0, stream>>>(x, Wq, Wk, Wv, Wo, Xh, Wqkv, Woh);
  gemm_qkv<<<dim3(24, 32), 256, 0, stream>>>(Xh, Wqkv, QKV2, Vt, 1024);
  rope_qk<<<4096, 256, 0, stream>>>(QKV2, Qh, Kh);
  attn<<<1024, 128, 0, stream>>>(Qh, Kh, Vt, Oh);
  gemm_bt<float, 128, 64><<<dim3(16, 32), 256, 0, stream>>>(Oh, Woh, out, 4096, 1024, 1024);
}